// Round 12
// baseline (71.191 us; speedup 1.0000x reference)
//
#include <hip/hip_runtime.h>

// ConvTranspose4d via bf16 MFMA (R12 = R11 + dwordx2 PAIR loads).
// Gather form: out[co,f,od,oh,ow] = sum_{ci,i,kd,kh,kw} x[ci,f+i,id,ih,iw]*W[ci,co,i,kd,kh,kw]
//   id=(od+1-kd)/2 parity-valid; kd in {0,2} (od odd) or {1} (od even); same for kh.
//   kw: ow even -> {1}; ow odd -> {0,2}. iw pair (n, n+1) covers all kw per column pair.
// GEMM per class (pd,ph): M=16 (co 0..7 + zero pad), K = 8ci*3i*ND*NH*2c, N = 16 cols
//   of one ow parity; one wave does even+odd tiles sharing B loads.
// R12 change: each PAIR was 2 scalar dword loads (x[n], x[n+1]) -> now ONE dwordx2.
//   R11 accounting: 4.5M VMEM instrs (~17.4K/CU) dominate the cycle budget via
//   VMEM-issue + TA line-scan; MFMA only ~5%. Halving instruction count is the lever.
//   OOB guard: n==47 lanes load at p-1 and select (x0=xv.y, x1=xv.y) == old clamped
//   values bit-exactly (x[48] may be OOB garbage/NaN -> would poison via 0-weight slot).

typedef float  f32x4  __attribute__((ext_vector_type(4)));
typedef short  bf16x8 __attribute__((ext_vector_type(8)));   // 8 bf16 (guide Sec.3)
typedef unsigned int u32;
typedef u32    u32x4  __attribute__((ext_vector_type(4)));
typedef float  f2u    __attribute__((ext_vector_type(2), aligned(4)));

namespace {
constexpr int T_ = 8, D_ = 24, H_ = 48, W_ = 48;
constexpr int TO = 6, DO_ = 47, HO = 95, WO = 95;
constexpr int XCS = T_ * D_ * H_ * W_;
constexpr int XFS = D_ * H_ * W_;
constexpr int XDS = H_ * W_;
constexpr long OCS = (long)TO * DO_ * HO * WO;
constexpr int OFS = DO_ * HO * WO;
constexpr int ODS = HO * WO;

// classes: 0:(ND2,NH2) 1:(2,1) 2:(1,2) 3:(1,1); groups = K_pad/8
constexpr int AG[4] = {24, 12, 12, 8};
// short-offsets for (class*2 + pw); each (c,pw) block = AG[c]*128 shorts
constexpr int AOFFC[8] = {0, 3072, 6144, 7680, 9216, 10752, 12288, 13312};  // end 14336

__global__ __launch_bounds__(256) void pack_kernel(const float* __restrict__ w,
                                                   unsigned short* __restrict__ A) {
  const int tid = blockIdx.x * 256 + threadIdx.x;
  const int nthr = gridDim.x * 256;
  const int NDs[4] = {2, 2, 1, 1}, NHs[4] = {2, 1, 2, 1}, KR[4] = {192, 96, 96, 48};
  for (int c = 0; c < 4; ++c) {
    for (int pw = 0; pw < 2; ++pw) {
      const int cnt = AG[c] * 128;
      for (int e = tid; e < cnt; e += nthr) {
        const int j = e & 7, r = (e >> 3) & 15, g = e >> 7;
        const int k = g * 8 + j;
        float v = 0.f;
        if (r < 8 && k < KR[c]) {
          int gg, a = 0, b = 0, cc;
          if (c == 0)      { gg = g;               a = (j >> 2) & 1; b = (j >> 1) & 1; cc = j & 1; }
          else if (c == 1) { gg = 2 * g + (j >> 2); a = (j >> 1) & 1;                  cc = j & 1; }
          else if (c == 2) { gg = 2 * g + (j >> 2); b = (j >> 1) & 1;                  cc = j & 1; }
          else             { gg = 4 * g + (j >> 1);                                    cc = j & 1; }
          if (gg < 24) {
            const int ci = gg / 3, i = gg - 3 * (gg / 3);
            const int kd = (NDs[c] == 2) ? (a ? 2 : 0) : 1;
            const int kh = (NHs[c] == 2) ? (b ? 2 : 0) : 1;
            int kw = -1;
            if (cc == 0) kw = pw ? 0 : 1;
            else if (pw) kw = 2;                      // pw==0,c==1 -> zero slot
            if (kw >= 0) v = w[ci * 648 + r * 81 + i * 27 + kd * 9 + kh * 3 + kw];
          }
        }
        u32 u = __float_as_uint(v);
        u += 0x7FFFu + ((u >> 16) & 1u);              // RNE to bf16
        A[AOFFC[c * 2 + pw] + e] = (unsigned short)(u >> 16);
      }
    }
  }
}

template<int PD, int PH>
__device__ __forceinline__ void wave_body(
    const float* __restrict__ x, const unsigned short* __restrict__ A,
    float* __restrict__ out, int f, int od, int oh, int blk, int lane)
{
  constexpr int CLS = (PD && PH) ? 0 : PD ? 1 : PH ? 2 : 3;
  constexpr int NSTEP = (CLS == 0) ? 6 : (CLS == 3) ? 2 : 3;
  const int c15 = lane & 15, q = lane >> 4;
  const int n = blk * 16 + c15;                       // iw base; x[n], x[n+1] feed this col-pair
  const int id0 = PD ? ((od + 1) >> 1) : (od >> 1);
  const int ih0 = PH ? ((oh + 1) >> 1) : (oh >> 1);

  bf16x8 afe[NSTEP], afo[NSTEP];
  {
    const unsigned short* Ae = A + AOFFC[CLS * 2 + 0];
    const unsigned short* Ao = A + AOFFC[CLS * 2 + 1];
    #pragma unroll
    for (int s = 0; s < NSTEP; ++s) {
      const int g = s * 4 + q;
      afe[s] = *reinterpret_cast<const bf16x8*>(Ae + g * 128 + c15 * 8);
      afo[s] = *reinterpret_cast<const bf16x8*>(Ao + g * 128 + c15 * 8);
    }
  }
  f32x4 accE = {0.f, 0.f, 0.f, 0.f}, accO = {0.f, 0.f, 0.f, 0.f};
  const int off = (n < 47) ? 0 : 1;                   // last-column clamp (lane-const)
  const int pb = f * XFS + id0 * XDS + ih0 * W_ + n - off;

  // ONE dwordx2 load per PAIR (R12). off==1 lanes: xv=(x[46],x[47]) -> x0=x1=x[47],
  // bit-identical to R11's clamped values; no OOB read past the array.
  auto PAIR = [&](const float* p, u32& de, u32& dq) {
    const f2u xv = *reinterpret_cast<const f2u*>(p);
    const u32 w0 = __float_as_uint(xv.x), w1 = __float_as_uint(xv.y);
    const u32 bl = off ? w1 : w0;                     // x[n]
    const u32 bh = w1;                                // x[n+1] (or clamp)
    de = __builtin_amdgcn_perm(bh, bl, 0x07060302u);  // lo16=bf(x[n]) kw1, hi16=bf(x[n+1]) zeroA
    dq = __builtin_amdgcn_perm(bl, bh, 0x07060302u);  // lo16=bf(x[n+1]) kw0, hi16=bf(x[n]) kw2
  };

  #pragma unroll
  for (int s = 0; s < NSTEP; ++s) {
    const int G = s * 4 + q;
    u32 dE[4], dO[4];
    if constexpr (CLS == 0) {                         // 8-group = one (ci,i); j=(a,b,c)
      const int ci = G / 3, i = G - 3 * (G / 3);
      const float* p0 = x + pb + ci * XCS + i * XFS;
      PAIR(p0,            dE[0], dO[0]);
      PAIR(p0 - W_,       dE[1], dO[1]);
      PAIR(p0 - XDS,      dE[2], dO[2]);
      PAIR(p0 - XDS - W_, dE[3], dO[3]);
    } else if constexpr (CLS == 1) {                  // j=(gpar,a,c)
      const int g0 = 2 * G, g1 = 2 * G + 1;
      const int c0 = g0 / 3, i0 = g0 - 3 * (g0 / 3);
      const int c1 = g1 / 3, i1 = g1 - 3 * (g1 / 3);
      const float* p0 = x + pb + c0 * XCS + i0 * XFS;
      const float* p1 = x + pb + c1 * XCS + i1 * XFS;
      PAIR(p0,       dE[0], dO[0]);
      PAIR(p0 - XDS, dE[1], dO[1]);
      PAIR(p1,       dE[2], dO[2]);
      PAIR(p1 - XDS, dE[3], dO[3]);
    } else if constexpr (CLS == 2) {                  // j=(gpar,b,c)
      const int g0 = 2 * G, g1 = 2 * G + 1;
      const int c0 = g0 / 3, i0 = g0 - 3 * (g0 / 3);
      const int c1 = g1 / 3, i1 = g1 - 3 * (g1 / 3);
      const float* p0 = x + pb + c0 * XCS + i0 * XFS;
      const float* p1 = x + pb + c1 * XCS + i1 * XFS;
      PAIR(p0,      dE[0], dO[0]);
      PAIR(p0 - W_, dE[1], dO[1]);
      PAIR(p1,      dE[2], dO[2]);
      PAIR(p1 - W_, dE[3], dO[3]);
    } else {                                          // j=(g&3,c); pad k>=48 -> clamp, A=0
      #pragma unroll
      for (int d = 0; d < 4; ++d) {
        int gg = 4 * G + d; gg = (gg > 23) ? 23 : gg;
        const int ci = gg / 3, i = gg - 3 * (gg / 3);
        PAIR(x + pb + ci * XCS + i * XFS, dE[d], dO[d]);
      }
    }
    const u32x4 ue = {dE[0], dE[1], dE[2], dE[3]};
    const u32x4 uo = {dO[0], dO[1], dO[2], dO[3]};
    accE = __builtin_amdgcn_mfma_f32_16x16x32_bf16(afe[s], __builtin_bit_cast(bf16x8, ue), accE, 0, 0, 0);
    accO = __builtin_amdgcn_mfma_f32_16x16x32_bf16(afo[s], __builtin_bit_cast(bf16x8, uo), accO, 0, 0, 0);
  }

  if (lane < 32) {                                    // rows 0..7 = co; rows 8..15 discarded
    const long ob = (long)f * OFS + (long)od * ODS + (long)oh * HO + blk * 32 + 2 * c15;
    const bool full = !(blk == 2 && c15 == 15);       // ow=95 doesn't exist
    #pragma unroll
    for (int j = 0; j < 4; ++j) {
      float* po = out + (long)(q * 4 + j) * OCS + ob;
      if (full) { f2u v; v.x = accE[j]; v.y = accO[j]; *reinterpret_cast<f2u*>(po) = v; }
      else      { po[0] = accE[j]; }
    }
  }
}

constexpr int NWAVES = 6 * 47 * 95 * 3;               // 80370
constexpr int NBLK = (NWAVES + 3) / 4;                // 20093

__global__ __launch_bounds__(256) void convt4d_kernel(
    const float* __restrict__ x, const unsigned short* __restrict__ A,
    float* __restrict__ out)
{
  const int wid = blockIdx.x * 4 + (threadIdx.x >> 6);
  if (wid >= NWAVES) return;
  const int lane = threadIdx.x & 63;
  const int blk = wid % 3;
  int rest = wid / 3;
  const int oh = rest % 95; rest /= 95;
  const int od = rest % 47; const int f = rest / 47;
  if (od & 1) {
    if (oh & 1) wave_body<1, 1>(x, A, out, f, od, oh, blk, lane);
    else        wave_body<1, 0>(x, A, out, f, od, oh, blk, lane);
  } else {
    if (oh & 1) wave_body<0, 1>(x, A, out, f, od, oh, blk, lane);
    else        wave_body<0, 0>(x, A, out, f, od, oh, blk, lane);
  }
}
}  // namespace

extern "C" void kernel_launch(void* const* d_in, const int* in_sizes, int n_in,
                              void* d_out, int out_size, void* d_ws, size_t ws_size,
                              hipStream_t stream) {
  const float* x = (const float*)d_in[0];
  const float* w = (const float*)d_in[1];
  float* out = (float*)d_out;
  unsigned short* A = (unsigned short*)d_ws;          // 14336 shorts = 28 KB
  hipLaunchKernelGGL(pack_kernel, dim3(8), dim3(256), 0, stream, w, A);
  hipLaunchKernelGGL(convt4d_kernel, dim3(NBLK), dim3(256), 0, stream, x, A, out);
}

// Round 13
// 58.548 us; speedup vs baseline: 1.2159x; 1.2159x over previous
//
#include <hip/hip_runtime.h>

// ConvTranspose4d via bf16 MFMA (R13 = R11 + batched K-step loads + XCD swizzle).
// Gather form: out[co,f,od,oh,ow] = sum_{ci,i,kd,kh,kw} x[ci,f+i,id,ih,iw]*W[ci,co,i,kd,kh,kw]
//   id=(od+1-kd)/2 parity-valid; kd in {0,2} (od odd) or {1} (od even); same for kh.
//   kw: ow even -> {1}; ow odd -> {0,2}. iw pair (n, n+1) covers all kw per column pair.
// GEMM per class (pd,ph): M=16 (co 0..7 + pad), K = 8ci*3i*ND*NH*2c, N = 16 cols/parity;
//   one wave does even+odd tiles sharing B loads. A packed to d_ws (bf16) by pack_kernel.
// R13 changes vs R11 (63.7us):
//   (1) loads for 3 K-steps (2 for class3) issued together into reg arrays, then
//       sched_barrier(0), then perms+MFMA -> stalls/wave: 6->2 / 3->1 / 2->1.
//       R11 post-mortem: ~400cyc exposed per step, lockstep waves; issue floor ~25K cyc
//       vs 150K measured. FP order unchanged -> absmax bit-identical.
//   (2) bijective XCD swizzle (m204): consecutive wids share x rows -> same-XCD L2.
//       Signature split: FETCH_SIZE isolates (2); dur-vs-FETCH isolates (1).
// R12 lesson: dwordx2 at 4B-align regressed (71us) -> keep 2 aligned dword loads/PAIR.

typedef float  f32x4  __attribute__((ext_vector_type(4)));
typedef short  bf16x8 __attribute__((ext_vector_type(8)));   // 8 bf16 (4 VGPR)
typedef unsigned int u32;
typedef u32    u32x4  __attribute__((ext_vector_type(4)));
typedef float  f2u    __attribute__((ext_vector_type(2), aligned(4)));

namespace {
constexpr int T_ = 8, D_ = 24, H_ = 48, W_ = 48;
constexpr int TO = 6, DO_ = 47, HO = 95, WO = 95;
constexpr int XCS = T_ * D_ * H_ * W_;
constexpr int XFS = D_ * H_ * W_;
constexpr int XDS = H_ * W_;
constexpr long OCS = (long)TO * DO_ * HO * WO;
constexpr int OFS = DO_ * HO * WO;
constexpr int ODS = HO * WO;

// classes: 0:(ND2,NH2) 1:(2,1) 2:(1,2) 3:(1,1); groups = K_pad/8
constexpr int AG[4] = {24, 12, 12, 8};
constexpr int AOFFC[8] = {0, 3072, 6144, 7680, 9216, 10752, 12288, 13312};  // end 14336

__global__ __launch_bounds__(256) void pack_kernel(const float* __restrict__ w,
                                                   unsigned short* __restrict__ A) {
  const int tid = blockIdx.x * 256 + threadIdx.x;
  const int nthr = gridDim.x * 256;
  const int NDs[4] = {2, 2, 1, 1}, NHs[4] = {2, 1, 2, 1}, KR[4] = {192, 96, 96, 48};
  for (int c = 0; c < 4; ++c) {
    for (int pw = 0; pw < 2; ++pw) {
      const int cnt = AG[c] * 128;
      for (int e = tid; e < cnt; e += nthr) {
        const int j = e & 7, r = (e >> 3) & 15, g = e >> 7;
        const int k = g * 8 + j;
        float v = 0.f;
        if (r < 8 && k < KR[c]) {
          int gg, a = 0, b = 0, cc;
          if (c == 0)      { gg = g;               a = (j >> 2) & 1; b = (j >> 1) & 1; cc = j & 1; }
          else if (c == 1) { gg = 2 * g + (j >> 2); a = (j >> 1) & 1;                  cc = j & 1; }
          else if (c == 2) { gg = 2 * g + (j >> 2); b = (j >> 1) & 1;                  cc = j & 1; }
          else             { gg = 4 * g + (j >> 1);                                    cc = j & 1; }
          if (gg < 24) {
            const int ci = gg / 3, i = gg - 3 * (gg / 3);
            const int kd = (NDs[c] == 2) ? (a ? 2 : 0) : 1;
            const int kh = (NHs[c] == 2) ? (b ? 2 : 0) : 1;
            int kw = -1;
            if (cc == 0) kw = pw ? 0 : 1;
            else if (pw) kw = 2;                      // pw==0,cc==1 -> zero slot
            if (kw >= 0) v = w[ci * 648 + r * 81 + i * 27 + kd * 9 + kh * 3 + kw];
          }
        }
        u32 u = __float_as_uint(v);
        u += 0x7FFFu + ((u >> 16) & 1u);              // RNE to bf16
        A[AOFFC[c * 2 + pw] + e] = (unsigned short)(u >> 16);
      }
    }
  }
}

template<int PD, int PH>
__device__ __forceinline__ void wave_body(
    const float* __restrict__ x, const unsigned short* __restrict__ A,
    float* __restrict__ out, int f, int od, int oh, int blk, int lane)
{
  constexpr int CLS = (PD && PH) ? 0 : PD ? 1 : PH ? 2 : 3;
  constexpr int NSTEP = (CLS == 0) ? 6 : (CLS == 3) ? 2 : 3;
  constexpr int BSZ   = (CLS == 3) ? 2 : 3;            // K-steps per load batch
  constexpr int NBATCH = NSTEP / BSZ;                  // 2 / 1 / 1 / 1
  const int c15 = lane & 15, q = lane >> 4;
  const int n = blk * 16 + c15;                        // iw base; x[n], x[n+1] feed col pair
  const int id0 = PD ? ((od + 1) >> 1) : (od >> 1);
  const int ih0 = PH ? ((oh + 1) >> 1) : (oh >> 1);

  bf16x8 afe[NSTEP], afo[NSTEP];
  {
    const unsigned short* Ae = A + AOFFC[CLS * 2 + 0];
    const unsigned short* Ao = A + AOFFC[CLS * 2 + 1];
    #pragma unroll
    for (int s = 0; s < NSTEP; ++s) {
      const int g = s * 4 + q;
      afe[s] = *reinterpret_cast<const bf16x8*>(Ae + g * 128 + c15 * 8);
      afo[s] = *reinterpret_cast<const bf16x8*>(Ao + g * 128 + c15 * 8);
    }
  }
  f32x4 accE = {0.f, 0.f, 0.f, 0.f}, accO = {0.f, 0.f, 0.f, 0.f};
  const int hs = (n < 47) ? 1 : 0;                     // clamp last x[n+1] (zero-A slots only)
  const int pb = f * XFS + id0 * XDS + ih0 * W_ + n;

  // 4 row pointers for step-group G, per class (same as R11)
  auto ptrs = [&](int G, const float* p[4]) {
    if constexpr (CLS == 0) {                          // one (ci,i); j=(a,b,c)
      const int ci = G / 3, i = G - 3 * (G / 3);
      const float* p0 = x + pb + ci * XCS + i * XFS;
      p[0] = p0; p[1] = p0 - W_; p[2] = p0 - XDS; p[3] = p0 - XDS - W_;
    } else if constexpr (CLS == 1) {                   // j=(gpar,a,c)
      const int g0 = 2 * G, g1 = 2 * G + 1;
      const float* p0 = x + pb + (g0 / 3) * XCS + (g0 - 3 * (g0 / 3)) * XFS;
      const float* p1 = x + pb + (g1 / 3) * XCS + (g1 - 3 * (g1 / 3)) * XFS;
      p[0] = p0; p[1] = p0 - XDS; p[2] = p1; p[3] = p1 - XDS;
    } else if constexpr (CLS == 2) {                   // j=(gpar,b,c)
      const int g0 = 2 * G, g1 = 2 * G + 1;
      const float* p0 = x + pb + (g0 / 3) * XCS + (g0 - 3 * (g0 / 3)) * XFS;
      const float* p1 = x + pb + (g1 / 3) * XCS + (g1 - 3 * (g1 / 3)) * XFS;
      p[0] = p0; p[1] = p0 - W_; p[2] = p1; p[3] = p1 - W_;
    } else {                                           // j=(g&3,c); pad k>=48 clamped (A=0)
      #pragma unroll
      for (int d = 0; d < 4; ++d) {
        int gg = 4 * G + d; gg = (gg > 23) ? 23 : gg;
        p[d] = x + pb + (gg / 3) * XCS + (gg - 3 * (gg / 3)) * XFS;
      }
    }
  };

  #pragma unroll
  for (int bt = 0; bt < NBATCH; ++bt) {
    u32 bl[BSZ][4], bh[BSZ][4];
    // issue ALL loads of this batch (BSZ steps x 4 PAIRs x 2 dwords), no uses between
    #pragma unroll
    for (int sb = 0; sb < BSZ; ++sb) {
      const int G = (bt * BSZ + sb) * 4 + q;
      const float* p[4]; ptrs(G, p);
      #pragma unroll
      for (int d = 0; d < 4; ++d) {
        bl[sb][d] = __float_as_uint(p[d][0]);          // x[n]
        bh[sb][d] = __float_as_uint(p[d][hs]);         // x[n+1] (or clamp at n=47)
      }
    }
    __builtin_amdgcn_sched_barrier(0);                 // pin: loads above, consumers below
    #pragma unroll
    for (int sb = 0; sb < BSZ; ++sb) {
      const int s = bt * BSZ + sb;
      u32 dE[4], dO[4];
      #pragma unroll
      for (int d = 0; d < 4; ++d) {
        // lo16=bf(x[n]) (kw1 / E), hi16=bf(x[n+1]); and the swapped packing for O
        dE[d] = __builtin_amdgcn_perm(bh[sb][d], bl[sb][d], 0x07060302u);
        dO[d] = __builtin_amdgcn_perm(bl[sb][d], bh[sb][d], 0x07060302u);
      }
      const u32x4 ue = {dE[0], dE[1], dE[2], dE[3]};
      const u32x4 uo = {dO[0], dO[1], dO[2], dO[3]};
      accE = __builtin_amdgcn_mfma_f32_16x16x32_bf16(afe[s], __builtin_bit_cast(bf16x8, ue), accE, 0, 0, 0);
      accO = __builtin_amdgcn_mfma_f32_16x16x32_bf16(afo[s], __builtin_bit_cast(bf16x8, uo), accO, 0, 0, 0);
    }
  }

  if (lane < 32) {                                     // rows 0..7 = co; rows 8..15 pad
    const long ob = (long)f * OFS + (long)od * ODS + (long)oh * HO + blk * 32 + 2 * c15;
    const bool full = !(blk == 2 && c15 == 15);        // ow=95 doesn't exist
    #pragma unroll
    for (int j = 0; j < 4; ++j) {
      float* po = out + (long)(q * 4 + j) * OCS + ob;
      if (full) { f2u v; v.x = accE[j]; v.y = accO[j]; *reinterpret_cast<f2u*>(po) = v; }
      else      { po[0] = accE[j]; }
    }
  }
}

constexpr int NWAVES = 6 * 47 * 95 * 3;                // 80370
constexpr int NBLK = (NWAVES + 3) / 4;                 // 20093

__global__ __launch_bounds__(256) void convt4d_kernel(
    const float* __restrict__ x, const unsigned short* __restrict__ A,
    float* __restrict__ out)
{
  // bijective XCD swizzle (m204; NBLK%8=5): consecutive work ids -> same XCD L2
  constexpr int qq = NBLK / 8, rr = NBLK % 8;          // 2511, 5
  const int bid = blockIdx.x;
  const int xcd = bid % 8, ii = bid / 8;
  const int base = (xcd < rr) ? xcd * (qq + 1) : rr * (qq + 1) + (xcd - rr) * qq;
  const int wid = (base + ii) * 4 + (threadIdx.x >> 6);
  if (wid >= NWAVES) return;
  const int lane = threadIdx.x & 63;
  const int blk = wid % 3;
  int rest = wid / 3;
  const int oh = rest % 95; rest /= 95;
  const int od = rest % 47; const int f = rest / 47;
  if (od & 1) {
    if (oh & 1) wave_body<1, 1>(x, A, out, f, od, oh, blk, lane);
    else        wave_body<1, 0>(x, A, out, f, od, oh, blk, lane);
  } else {
    if (oh & 1) wave_body<0, 1>(x, A, out, f, od, oh, blk, lane);
    else        wave_body<0, 0>(x, A, out, f, od, oh, blk, lane);
  }
}
}  // namespace

extern "C" void kernel_launch(void* const* d_in, const int* in_sizes, int n_in,
                              void* d_out, int out_size, void* d_ws, size_t ws_size,
                              hipStream_t stream) {
  const float* x = (const float*)d_in[0];
  const float* w = (const float*)d_in[1];
  float* out = (float*)d_out;
  unsigned short* A = (unsigned short*)d_ws;           // 14336 shorts = 28 KB
  hipLaunchKernelGGL(pack_kernel, dim3(8), dim3(256), 0, stream, w, A);
  hipLaunchKernelGGL(convt4d_kernel, dim3(NBLK), dim3(256), 0, stream, x, A, out);
}